// Round 1
// baseline (282.967 us; speedup 1.0000x reference)
//
#include <hip/hip_runtime.h>
#include <math.h>

// Problem constants (DynamicElementAggregator): B=2, N=1024, M=1024, D=768, H=72
#define B_ 2
#define N_ 1024
#define M_ 1024
#define D_ 768
#define F_ 384   // D/2
#define H_ 72
#define ROWS_ 8  // rows per MLP block

// Raw router weights buffer: 2048 x 72 f32 (576 KB) — module-scope device
// memory, so we don't depend on ws_size. Fully overwritten every call.
__device__ float g_rw[B_ * N_ * H_];

// ---------------- Kernel A: router MLP (x @ W1 -> GELU -> @ W2 + b2) --------
// grid 256, block 384. Each block computes 8 rows of raw_weights.
// Thread f owns hidden column f. x loads are wave-uniform (scalarizable);
// W1 loads are coalesced across threads (f contiguous).
__global__ __launch_bounds__(384) void mlp_kernel(
    const float* __restrict__ x, const float* __restrict__ W1,
    const float* __restrict__ b1, const float* __restrict__ W2,
    const float* __restrict__ b2)
{
    const int f = threadIdx.x;            // 0..383
    const int row0 = blockIdx.x * ROWS_;  // global row (b*N+n flattened)

    __shared__ float h_lds[ROWS_][F_ + 4];  // pitch 388 floats (16B-aligned rows)

    float acc[ROWS_];
#pragma unroll
    for (int r = 0; r < ROWS_; ++r) acc[r] = 0.0f;

    // ---- layer 1: h = x @ W1 ----
    for (int d = 0; d < D_; d += 4) {
        float4 xv[ROWS_];
#pragma unroll
        for (int r = 0; r < ROWS_; ++r)
            xv[r] = *reinterpret_cast<const float4*>(&x[(row0 + r) * D_ + d]);
        const float w0 = W1[(d + 0) * F_ + f];
        const float w1 = W1[(d + 1) * F_ + f];
        const float w2 = W1[(d + 2) * F_ + f];
        const float w3 = W1[(d + 3) * F_ + f];
#pragma unroll
        for (int r = 0; r < ROWS_; ++r) {
            acc[r] = fmaf(xv[r].x, w0, acc[r]);
            acc[r] = fmaf(xv[r].y, w1, acc[r]);
            acc[r] = fmaf(xv[r].z, w2, acc[r]);
            acc[r] = fmaf(xv[r].w, w3, acc[r]);
        }
    }

    // bias + exact GELU -> LDS
    const float b1f = b1[f];
#pragma unroll
    for (int r = 0; r < ROWS_; ++r) {
        float v = acc[r] + b1f;
        h_lds[r][f] = 0.5f * v * (1.0f + erff(v * 0.70710678118654752f));
    }
    __syncthreads();

    // ---- layer 2: rw = h @ W2 + b2  (576 outputs; threads take o and o+384)
#pragma unroll 1
    for (int o = threadIdx.x; o < ROWS_ * H_; o += 384) {
        const int r = o / H_;
        const int c = o % H_;
        float s = 0.0f;
#pragma unroll 4
        for (int k = 0; k < F_; k += 4) {
            const float4 hv = *reinterpret_cast<const float4*>(&h_lds[r][k]);
            s = fmaf(hv.x, W2[(k + 0) * H_ + c], s);
            s = fmaf(hv.y, W2[(k + 1) * H_ + c], s);
            s = fmaf(hv.z, W2[(k + 2) * H_ + c], s);
            s = fmaf(hv.w, W2[(k + 3) * H_ + c], s);
        }
        g_rw[(row0 + r) * H_ + c] = s + b2[c];
    }
}

// ---------------- Kernel B: weighted combine over heads ---------------------
// grid 2048 (one block per (b,n)), block 256. Thread t owns float4 at m=4t.
// Streams 72 contiguous 4KB score rows per block; pure HBM-bound.
__global__ __launch_bounds__(256) void combine_kernel(
    const float* __restrict__ scores, const float* __restrict__ bias,
    float* __restrict__ out)
{
    const int bn = blockIdx.x;            // 0..2047
    const int b = bn >> 10;
    const int n = bn & (N_ - 1);

    __shared__ float w[H_];
    if (threadIdx.x < H_) w[threadIdx.x] = g_rw[bn * H_ + threadIdx.x];
    __syncthreads();

    const float4* __restrict__ sp = reinterpret_cast<const float4*>(scores);
    // element index of scores[b][h][n][m] = ((b*H + h)*N + n)*M + m
    int idx = ((b * H_) * N_ + n) * (M_ / 4) + threadIdx.x;
    const int hstride = N_ * (M_ / 4);    // 262144 float4 per head

    float4 acc = make_float4(0.f, 0.f, 0.f, 0.f);
#pragma unroll 8
    for (int h = 0; h < H_; ++h) {
        const float4 s = sp[idx];
        const float wh = w[h];
        acc.x = fmaf(wh, s.x, acc.x);
        acc.y = fmaf(wh, s.y, acc.y);
        acc.z = fmaf(wh, s.z, acc.z);
        acc.w = fmaf(wh, s.w, acc.w);
        idx += hstride;
    }

    const float bv = bias[0];
    float4 r;
    r.x = acc.x + bv; r.y = acc.y + bv; r.z = acc.z + bv; r.w = acc.w + bv;
    reinterpret_cast<float4*>(out)[bn * (M_ / 4) + threadIdx.x] = r;
}

extern "C" void kernel_launch(void* const* d_in, const int* in_sizes, int n_in,
                              void* d_out, int out_size, void* d_ws, size_t ws_size,
                              hipStream_t stream) {
    const float* x      = (const float*)d_in[0];
    const float* scores = (const float*)d_in[1];
    const float* W1     = (const float*)d_in[2];
    const float* b1     = (const float*)d_in[3];
    const float* W2     = (const float*)d_in[4];
    const float* b2     = (const float*)d_in[5];
    const float* bias   = (const float*)d_in[6];
    float* out = (float*)d_out;

    mlp_kernel<<<(B_ * N_) / ROWS_, 384, 0, stream>>>(x, W1, b1, W2, b2);
    combine_kernel<<<B_ * N_, 256, 0, stream>>>(scores, bias, out);
}

// Round 2
// 239.145 us; speedup vs baseline: 1.1832x; 1.1832x over previous
//
#include <hip/hip_runtime.h>
#include <math.h>

// DynamicElementAggregator: B=2, N=1024, M=1024, D=768, F=384, H=72
#define B_ 2
#define N_ 1024
#define M_ 1024
#define D_ 768
#define F_ 384
#define H_ 72

// Module-scope scratch (no d_ws dependence). All fully rewritten each call.
__device__ float g_h[B_ * N_ * F_];    // 3 MB    hidden activations
__device__ float g_rw[B_ * N_ * H_];   // 576 KB  raw router weights
__device__ float g_w2t[H_ * F_];       // 108 KB  W2 transposed [H][F]

// ---- K0: transpose W2 [F][H] -> [H][F] so K2 reads both operands float4 ----
__global__ __launch_bounds__(256) void k0_transpose(const float* __restrict__ W2) {
    int i = blockIdx.x * 256 + threadIdx.x;   // over H*F = 27648
    if (i < H_ * F_) {
        int c = i / F_;
        int k = i - c * F_;
        g_w2t[i] = W2[k * H_ + c];            // coalesced write, strided read (L2)
    }
}

// ---- K1: h = GELU(x @ W1 + b1) -----------------------------------------
// 256 blocks x 384 threads; 8 rows/block. x staged in LDS (broadcast b128
// reads), W1 coalesced dword loads across f, 8-row FMA amortization.
__global__ __launch_bounds__(384) void k1_mlp1(const float* __restrict__ x,
                                               const float* __restrict__ W1,
                                               const float* __restrict__ b1) {
    const int f = threadIdx.x;
    const int row0 = blockIdx.x * 8;

    __shared__ float xs[8][D_];               // 24 KB
    {
        const float4* xg = reinterpret_cast<const float4*>(x + row0 * D_);
        float4* xl = reinterpret_cast<float4*>(&xs[0][0]);
#pragma unroll
        for (int i = 0; i < 4; ++i)           // 1536 float4 / 384 threads
            xl[threadIdx.x + i * 384] = xg[threadIdx.x + i * 384];
    }
    __syncthreads();

    float acc[8];
#pragma unroll
    for (int r = 0; r < 8; ++r) acc[r] = 0.0f;

#pragma unroll 2
    for (int d = 0; d < D_; d += 4) {
        const float w0 = W1[(d + 0) * F_ + f];
        const float w1v = W1[(d + 1) * F_ + f];
        const float w2v = W1[(d + 2) * F_ + f];
        const float w3v = W1[(d + 3) * F_ + f];
#pragma unroll
        for (int r = 0; r < 8; ++r) {
            const float4 xv = *reinterpret_cast<const float4*>(&xs[r][d]);
            acc[r] = fmaf(xv.x, w0, acc[r]);
            acc[r] = fmaf(xv.y, w1v, acc[r]);
            acc[r] = fmaf(xv.z, w2v, acc[r]);
            acc[r] = fmaf(xv.w, w3v, acc[r]);
        }
    }

    const float bb = b1[f];
#pragma unroll
    for (int r = 0; r < 8; ++r) {
        const float v = acc[r] + bb;
        g_h[(row0 + r) * F_ + f] = 0.5f * v * (1.0f + erff(v * 0.70710678118654752f));
    }
}

// ---- K2: rw = h @ W2 + b2 ------------------------------------------------
// One thread per output element (2048*72 = 147456 -> 576 blocks x 256).
// Both operand streams are contiguous float4 (thanks to g_w2t).
__global__ __launch_bounds__(256) void k2_mlp2(const float* __restrict__ b2) {
    const int gid = blockIdx.x * 256 + threadIdx.x;
    const int row = gid / H_;
    const int c = gid - row * H_;
    const float* __restrict__ hp = &g_h[row * F_];
    const float* __restrict__ wp = &g_w2t[c * F_];
    float s = 0.0f;
#pragma unroll 4
    for (int k = 0; k < F_; k += 4) {
        const float4 hv = *reinterpret_cast<const float4*>(hp + k);
        const float4 wv = *reinterpret_cast<const float4*>(wp + k);
        s = fmaf(hv.x, wv.x, s);
        s = fmaf(hv.y, wv.y, s);
        s = fmaf(hv.z, wv.z, s);
        s = fmaf(hv.w, wv.w, s);
    }
    g_rw[gid] = s + b2[c];
}

// ---- K3: final_matrix = sum_h rw[b,n,h] * scores[b,h,n,:] + bias ---------
// 4096 blocks (2 per (b,n) row) x 128 threads; thread owns one float4 of out.
// Pure HBM stream: 72 coalesced 1-2KB row-chunks per block.
__global__ __launch_bounds__(128) void k3_combine(const float* __restrict__ scores,
                                                  const float* __restrict__ bias,
                                                  float* __restrict__ out) {
    const int blk = blockIdx.x;        // 0..4095
    const int bn = blk >> 1;
    const int half = blk & 1;
    const int b = bn >> 10;
    const int n = bn & (N_ - 1);

    __shared__ float w[H_];
    if (threadIdx.x < H_) w[threadIdx.x] = g_rw[bn * H_ + threadIdx.x];
    __syncthreads();

    const float4* __restrict__ sp = reinterpret_cast<const float4*>(scores);
    int idx = ((b * H_) * N_ + n) * (M_ / 4) + half * 128 + threadIdx.x;
    const int hstr = N_ * (M_ / 4);    // 4 MB in float4 units

    float4 acc = make_float4(0.f, 0.f, 0.f, 0.f);
#pragma unroll 8
    for (int h = 0; h < H_; ++h) {
        const float4 s = sp[idx];
        const float wh = w[h];
        acc.x = fmaf(wh, s.x, acc.x);
        acc.y = fmaf(wh, s.y, acc.y);
        acc.z = fmaf(wh, s.z, acc.z);
        acc.w = fmaf(wh, s.w, acc.w);
        idx += hstr;
    }

    const float bv = bias[0];
    float4 r;
    r.x = acc.x + bv; r.y = acc.y + bv; r.z = acc.z + bv; r.w = acc.w + bv;
    reinterpret_cast<float4*>(out)[bn * (M_ / 4) + half * 128 + threadIdx.x] = r;
}

extern "C" void kernel_launch(void* const* d_in, const int* in_sizes, int n_in,
                              void* d_out, int out_size, void* d_ws, size_t ws_size,
                              hipStream_t stream) {
    const float* x      = (const float*)d_in[0];
    const float* scores = (const float*)d_in[1];
    const float* W1     = (const float*)d_in[2];
    const float* b1     = (const float*)d_in[3];
    const float* W2     = (const float*)d_in[4];
    const float* b2     = (const float*)d_in[5];
    const float* bias   = (const float*)d_in[6];
    float* out = (float*)d_out;

    k0_transpose<<<(H_ * F_ + 255) / 256, 256, 0, stream>>>(W2);
    k1_mlp1<<<(B_ * N_) / 8, 384, 0, stream>>>(x, W1, b1);
    k2_mlp2<<<(B_ * N_ * H_) / 256, 256, 0, stream>>>(b2);
    k3_combine<<<2 * B_ * N_, 128, 0, stream>>>(scores, bias, out);
}

// Round 5
// 143.923 us; speedup vs baseline: 1.9661x; 1.6616x over previous
//
#include <hip/hip_runtime.h>
#include <math.h>

// DynamicElementAggregator: B=2, N=1024, M=1024, D=768, F=384, H=72
#define B_ 2
#define N_ 1024
#define M_ 1024
#define D_ 768
#define F_ 384
#define H_ 72

typedef float f32x4 __attribute__((ext_vector_type(4)));

// Raw router weights (2048 x 72, 576 KB). Fully rewritten every call.
__device__ float g_rw[B_ * N_ * H_];

// ---- K1: full router MLP: rw = GELU(x@W1 + b1) @ W2 + b2 ------------------
// 256 blocks x 384 threads, 8 rows/block.
// Layer 1: thread f owns hidden col f; W1 loads coalesced (f contiguous),
//          x broadcast from LDS.
// Layer 2: lane -> output c (contiguous W2 row segments, L1-resident),
//          h broadcast from LDS.
__global__ __launch_bounds__(384) void mlp_kernel(
    const float* __restrict__ x, const float* __restrict__ W1,
    const float* __restrict__ b1, const float* __restrict__ W2,
    const float* __restrict__ b2)
{
    const int f = threadIdx.x;            // 0..383
    const int row0 = blockIdx.x * 8;

    __shared__ float xs[8][D_];           // 24 KB
    __shared__ float hs[8][F_ + 8];       // 12.25 KB, pitch 392 (16B-aligned)

    {   // stage x rows (coalesced float4)
        const f32x4* xg = reinterpret_cast<const f32x4*>(x + row0 * D_);
        f32x4* xl = reinterpret_cast<f32x4*>(&xs[0][0]);
#pragma unroll
        for (int i = 0; i < 4; ++i)       // 1536 float4 / 384 threads
            xl[threadIdx.x + i * 384] = xg[threadIdx.x + i * 384];
    }
    __syncthreads();

    float acc[8];
#pragma unroll
    for (int r = 0; r < 8; ++r) acc[r] = 0.0f;

#pragma unroll 4
    for (int d = 0; d < D_; d += 4) {     // 16 W1 loads in flight at unroll 4
        const float w0 = W1[(d + 0) * F_ + f];
        const float w1v = W1[(d + 1) * F_ + f];
        const float w2v = W1[(d + 2) * F_ + f];
        const float w3v = W1[(d + 3) * F_ + f];
#pragma unroll
        for (int r = 0; r < 8; ++r) {
            const float4 xv = *reinterpret_cast<const float4*>(&xs[r][d]);
            acc[r] = fmaf(xv.x, w0, acc[r]);
            acc[r] = fmaf(xv.y, w1v, acc[r]);
            acc[r] = fmaf(xv.z, w2v, acc[r]);
            acc[r] = fmaf(xv.w, w3v, acc[r]);
        }
    }

    const float bb = b1[f];
#pragma unroll
    for (int r = 0; r < 8; ++r) {
        const float v = acc[r] + bb;
        hs[r][f] = 0.5f * v * (1.0f + erff(v * 0.70710678118654752f));
    }
    __syncthreads();

    // ---- layer 2: 576 outputs (8 rows x 72 heads), o = r*72 + c ----
#pragma unroll 1
    for (int o = f; o < 8 * H_; o += 384) {
        const int r = o / H_;
        const int c = o - r * H_;         // consecutive lanes -> consecutive c
        float s = 0.0f;
#pragma unroll 4
        for (int k = 0; k < F_; k += 4) {
            const float4 hv = *reinterpret_cast<const float4*>(&hs[r][k]);
            s = fmaf(hv.x, W2[(k + 0) * H_ + c], s);
            s = fmaf(hv.y, W2[(k + 1) * H_ + c], s);
            s = fmaf(hv.z, W2[(k + 2) * H_ + c], s);
            s = fmaf(hv.w, W2[(k + 3) * H_ + c], s);
        }
        g_rw[row0 * H_ + o] = s + b2[c];  // == g_rw[(row0+r)*72 + c]
    }
}

// ---- K2: slab combine: out[b,n,:] = sum_h rw[b,n,h]*scores[b,h,n,:] + bias -
// 512 blocks x 256 threads; block owns 4 consecutive rows (same b).
// Per h the block reads one CONTIGUOUS 16 KB span (4 rows x 4 KB) -> good
// DRAM row locality. Nontemporal: scores/out touched exactly once.
// NOTE: grid MUST be (B*N)/4 = 512 — blk>>8 gives b, (blk&255)*4 gives n0.
__global__ __launch_bounds__(256) void combine_kernel(
    const float* __restrict__ scores, const float* __restrict__ bias,
    float* __restrict__ out)
{
    const int blk = blockIdx.x;           // 0..511
    const int b = blk >> 8;
    const int n0 = (blk & 255) * 4;
    const int t = threadIdx.x;

    __shared__ float w[4 * H_];           // weights for the 4 rows
    for (int i = t; i < 4 * H_; i += 256)
        w[i] = g_rw[((b << 10) + n0) * H_ + i];   // rows contiguous in g_rw
    __syncthreads();

    const f32x4* __restrict__ sp = reinterpret_cast<const f32x4*>(scores);
    const int base = ((b * H_) * N_ + n0) * (M_ / 4) + t;
    const int hstr = N_ * (M_ / 4);       // 262144 float4 per head

    f32x4 a0 = 0.f, a1 = 0.f, a2 = 0.f, a3 = 0.f;
#pragma unroll 2
    for (int h = 0; h < H_; ++h) {
        const int ib = base + h * hstr;
        const f32x4 v0 = __builtin_nontemporal_load(sp + ib);
        const f32x4 v1 = __builtin_nontemporal_load(sp + ib + 256);
        const f32x4 v2 = __builtin_nontemporal_load(sp + ib + 512);
        const f32x4 v3 = __builtin_nontemporal_load(sp + ib + 768);
        const float w0 = w[0 * H_ + h];
        const float w1 = w[1 * H_ + h];
        const float w2 = w[2 * H_ + h];
        const float w3 = w[3 * H_ + h];
#pragma unroll
        for (int j = 0; j < 4; ++j) {
            a0[j] = fmaf(w0, v0[j], a0[j]);
            a1[j] = fmaf(w1, v1[j], a1[j]);
            a2[j] = fmaf(w2, v2[j], a2[j]);
            a3[j] = fmaf(w3, v3[j], a3[j]);
        }
    }

    const float bv = bias[0];
    f32x4* __restrict__ op = reinterpret_cast<f32x4*>(out);
    const int obase = ((b << 10) + n0) * (M_ / 4) + t;
#pragma unroll
    for (int j = 0; j < 4; ++j) { a0[j] += bv; a1[j] += bv; a2[j] += bv; a3[j] += bv; }
    __builtin_nontemporal_store(a0, op + obase);
    __builtin_nontemporal_store(a1, op + obase + 256);
    __builtin_nontemporal_store(a2, op + obase + 512);
    __builtin_nontemporal_store(a3, op + obase + 768);
}

extern "C" void kernel_launch(void* const* d_in, const int* in_sizes, int n_in,
                              void* d_out, int out_size, void* d_ws, size_t ws_size,
                              hipStream_t stream) {
    const float* x      = (const float*)d_in[0];
    const float* scores = (const float*)d_in[1];
    const float* W1     = (const float*)d_in[2];
    const float* b1     = (const float*)d_in[3];
    const float* W2     = (const float*)d_in[4];
    const float* b2     = (const float*)d_in[5];
    const float* bias   = (const float*)d_in[6];
    float* out = (float*)d_out;

    mlp_kernel<<<(B_ * N_) / 8, 384, 0, stream>>>(x, W1, b1, W2, b2);
    combine_kernel<<<(B_ * N_) / 4, 256, 0, stream>>>(scores, bias, out);
}